// Round 1
// baseline (239.725 us; speedup 1.0000x reference)
//
#include <hip/hip_runtime.h>

// Problem constants
#define NPX    2097152                // 4*512*1024 pixels per head
#define NPX4   (NPX/4)
#define CH_STR 8192                   // 64*128
#define IMG_STR 155648                // 19*8192

// Workspace layout (bytes)
#define OFF_PROB  0ull                          // 2 heads * NPX floats = 16 MB
#define OFF_NLL   (2ull*NPX*4)                  // 16 MB
#define OFF_CTL   (4ull*NPX*4)                  // control region (u32 indexed)
// ctl layout in u32 units
#define CTL_HIST   0        // [3 levels][2 heads][4096]
#define CTL_PREFIX 24576    // [2]
#define CTL_KREM   24578    // [2]
#define CTL_THR    24580    // float[2]
#define CTL_SUM    24582    // float[2]
#define CTL_CNT    24584    // u32[2]
#define CTL_BSUM   24586    // float[8] (per-sample psum,nsum)
#define CTL_BCNT   24594    // u32[8]  (per-sample pc,nc)
#define CTL_U32S   24602

// ---------------------------------------------------------------------------
// Pass 1: upsample logits (align_corners) + log-softmax at target + store
// prob / nll arrays. One thread = 4 consecutive x outputs (share 6 input vals
// per channel instead of 16).
// ---------------------------------------------------------------------------
__global__ __launch_bounds__(256) void fused_pass1(
    const float* __restrict__ mp, const float* __restrict__ cp,
    const int* __restrict__ seg, float* __restrict__ probA, float* __restrict__ nllA)
{
    const float* pred = blockIdx.y ? cp : mp;
    float* prob = probA + (size_t)blockIdx.y * NPX;
    float* nll  = nllA  + (size_t)blockIdx.y * NPX;

    int g  = blockIdx.x * 256 + threadIdx.x;
    int P  = g << 2;
    int b  = P >> 19;
    int rem = P & 0x7FFFF;
    int y  = rem >> 10;
    int xb = rem & 1023;

    float fy = (float)y * (63.0f / 511.0f);
    int y0 = min((int)fy, 63);
    int y1 = min(y0 + 1, 63);
    float wy = fy - (float)y0;

    float wx[4]; bool s0m[4], s1m[4];
    float fx0 = (float)xb * (127.0f / 1023.0f);
    int X  = min((int)fx0, 126);          // x0 of first px; X+1 <= 127 always
    int X2 = min(X + 2, 127);
#pragma unroll
    for (int dx = 0; dx < 4; ++dx) {
        float fx = (float)(xb + dx) * (127.0f / 1023.0f);
        int x0 = min((int)fx, 127);
        int x1 = min(x0 + 1, 127);
        wx[dx]  = fx - (float)x0;
        s0m[dx] = (x0 == X);
        s1m[dx] = (x1 == X + 1);
    }

    int4 t4 = *(const int4*)(seg + P);
    int t[4] = {t4.x, t4.y, t4.z, t4.w};

    float s[4]  = {0.f, 0.f, 0.f, 0.f};
    float lt[4] = {0.f, 0.f, 0.f, 0.f};

    const float* r0 = pred + (size_t)b * IMG_STR + y0 * 128;
    const float* r1 = pred + (size_t)b * IMG_STR + y1 * 128;

    for (int c = 0; c < 19; ++c) {
        float c0 = r0[X], c1 = r0[X + 1], c2 = r0[X2];
        float d0 = r1[X], d1 = r1[X + 1], d2 = r1[X2];
#pragma unroll
        for (int dx = 0; dx < 4; ++dx) {
            float a0 = s0m[dx] ? c0 : c1;
            float a1 = s1m[dx] ? c1 : c2;
            float b0 = s0m[dx] ? d0 : d1;
            float b1 = s1m[dx] ? d1 : d2;
            float top = fmaf(wx[dx], a1 - a0, a0);
            float bot = fmaf(wx[dx], b1 - b0, b0);
            float l   = fmaf(wy, bot - top, top);
            s[dx] += __expf(l);
            lt[dx] = (c == t[dx]) ? l : lt[dx];
        }
        r0 += CH_STR; r1 += CH_STR;
    }

    float pr[4], nl[4];
#pragma unroll
    for (int dx = 0; dx < 4; ++dx) {
        float ls = __logf(s[dx]);
        float n  = ls - lt[dx];                 // -log softmax at target
        float p  = fminf(__expf(-n), 1.0f);     // prob at target, <= 1.0
        if (t[dx] == 255) { p = 1.0f; n = -1.0f; }   // invalid sentinel
        pr[dx] = p; nl[dx] = n;
    }
    *(float4*)(prob + P) = make_float4(pr[0], pr[1], pr[2], pr[3]);
    *(float4*)(nll  + P) = make_float4(nl[0], nl[1], nl[2], nl[3]);
}

// ---------------------------------------------------------------------------
// Radix-select histograms over float bit patterns (monotone for x >= 0).
// Level 0: bits[31:18] (<=4064), level 1: bits[17:6], level 2: bits[5:0].
// ---------------------------------------------------------------------------
__global__ __launch_bounds__(256) void hist_level(
    const float* __restrict__ probA, const unsigned* __restrict__ prefixA,
    unsigned* __restrict__ histA, int level)
{
    __shared__ unsigned h[4096];
    int head = blockIdx.y;
    const float4* prob = (const float4*)(probA + (size_t)head * NPX);
    unsigned* gh = histA + head * 4096;
    unsigned prefix = prefixA[head];
    for (int i = threadIdx.x; i < 4096; i += 256) h[i] = 0;
    __syncthreads();
    int stride = gridDim.x * 256;
    for (int i = blockIdx.x * 256 + threadIdx.x; i < NPX4; i += stride) {
        float4 p = prob[i];
        unsigned u[4] = {__float_as_uint(p.x), __float_as_uint(p.y),
                         __float_as_uint(p.z), __float_as_uint(p.w)};
#pragma unroll
        for (int k = 0; k < 4; ++k) {
            unsigned bv = u[k];
            if (level == 0) {
                atomicAdd(&h[bv >> 18], 1u);
            } else if (level == 1) {
                if ((bv >> 18) == prefix) atomicAdd(&h[(bv >> 6) & 0xFFFu], 1u);
            } else {
                if ((bv >> 6) == prefix) atomicAdd(&h[bv & 63u], 1u);
            }
        }
    }
    __syncthreads();
    for (int i = threadIdx.x; i < 4096; i += 256) {
        unsigned v = h[i];
        if (v) atomicAdd(&gh[i], v);
    }
}

__global__ __launch_bounds__(256) void select_level(
    const unsigned* __restrict__ histA, unsigned* __restrict__ prefixA,
    unsigned* __restrict__ kremA, float* __restrict__ thrA, int level, int bins)
{
    int head = blockIdx.x;
    const unsigned* h = histA + head * 4096;
    __shared__ unsigned chunk[256];
    __shared__ unsigned cpre[257];
    __shared__ float foundThr;
    if (threadIdx.x == 0) foundThr = 0.7f;

    int per  = (bins + 255) >> 8;
    int base = threadIdx.x * per;
    unsigned sum = 0;
    for (int i = 0; i < per; ++i) { int idx = base + i; if (idx < bins) sum += h[idx]; }
    chunk[threadIdx.x] = sum;
    __syncthreads();
    if (threadIdx.x == 0) {
        unsigned acc = 0;
        for (int i = 0; i < 256; ++i) { cpre[i] = acc; acc += chunk[i]; }
        cpre[256] = acc;
    }
    __syncthreads();
    unsigned K = (level == 0) ? 100000u : kremA[head];
    if (K > 0 && cpre[threadIdx.x] < K && K <= cpre[threadIdx.x + 1]) {
        unsigned acc = cpre[threadIdx.x];
        for (int i = 0; i < per; ++i) {
            int idx = base + i;
            unsigned c = (idx < bins) ? h[idx] : 0u;
            if (acc < K && K <= acc + c) {
                if (level == 0) {
                    prefixA[head] = (unsigned)idx; kremA[head] = K - acc;
                } else if (level == 1) {
                    prefixA[head] = (prefixA[head] << 12) | (unsigned)idx;
                    kremA[head] = K - acc;
                } else {
                    unsigned bitsv = (prefixA[head] << 6) | (unsigned)idx;
                    foundThr = fmaxf(0.7f, __uint_as_float(bitsv));
                }
                break;
            }
            acc += c;
        }
    }
    __syncthreads();
    if (level == 2 && threadIdx.x == 0) thrA[head] = foundThr;
}

// ---------------------------------------------------------------------------
// Final OHEM reduction: sum nll where (prob <= thr && valid)
// ---------------------------------------------------------------------------
__global__ __launch_bounds__(256) void reduce_ohem(
    const float* __restrict__ probA, const float* __restrict__ nllA,
    const float* __restrict__ thrA, float* __restrict__ sums, unsigned* __restrict__ cnts)
{
    int head = blockIdx.y;
    float thr = thrA[head];
    const float4* prob = (const float4*)(probA + (size_t)head * NPX);
    const float4* nl4  = (const float4*)(nllA  + (size_t)head * NPX);
    float fs = 0.f; unsigned ic = 0;
    int stride = gridDim.x * 256;
    for (int i = blockIdx.x * 256 + threadIdx.x; i < NPX4; i += stride) {
        float4 p = prob[i]; float4 n = nl4[i];
        if (p.x <= thr && n.x >= 0.f) { fs += n.x; ic++; }
        if (p.y <= thr && n.y >= 0.f) { fs += n.y; ic++; }
        if (p.z <= thr && n.z >= 0.f) { fs += n.z; ic++; }
        if (p.w <= thr && n.w >= 0.f) { fs += n.w; ic++; }
    }
    for (int o = 32; o; o >>= 1) {
        fs += __shfl_down(fs, o, 64);
        ic += (unsigned)__shfl_down((int)ic, o, 64);
    }
    __shared__ float lf[4]; __shared__ unsigned li[4];
    int wave = threadIdx.x >> 6, lane = threadIdx.x & 63;
    if (lane == 0) { lf[wave] = fs; li[wave] = ic; }
    __syncthreads();
    if (threadIdx.x == 0) {
        atomicAdd(&sums[head], lf[0] + lf[1] + lf[2] + lf[3]);
        atomicAdd(&cnts[head], li[0] + li[1] + li[2] + li[3]);
    }
}

// ---------------------------------------------------------------------------
// Boundary BCE: single pass, per-sample partial sums
// ---------------------------------------------------------------------------
__global__ __launch_bounds__(256) void boundary_kernel(
    const float* __restrict__ bp, const float* __restrict__ bg,
    float* __restrict__ bsums, unsigned* __restrict__ bcnts)
{
    int b = blockIdx.y;
    int g = blockIdx.x * 256 + threadIdx.x;
    int P = g << 2;                 // within-sample pixel index
    int y = P >> 10, xb = P & 1023;

    float fy = (float)y * (63.0f / 511.0f);
    int y0 = min((int)fy, 63);
    int y1 = min(y0 + 1, 63);
    float wy = fy - (float)y0;

    const float* r0 = bp + b * 8192 + y0 * 128;
    const float* r1 = bp + b * 8192 + y1 * 128;
    float fx0 = (float)xb * (127.0f / 1023.0f);
    int X  = min((int)fx0, 126);
    int X2 = min(X + 2, 127);
    float c0 = r0[X], c1 = r0[X + 1], c2 = r0[X2];
    float d0 = r1[X], d1 = r1[X + 1], d2 = r1[X2];

    float4 t4 = *(const float4*)(bg + (size_t)b * 524288 + P);
    float tv[4] = {t4.x, t4.y, t4.z, t4.w};

    float psum = 0.f, nsum = 0.f; unsigned pc = 0, nc = 0;
#pragma unroll
    for (int dx = 0; dx < 4; ++dx) {
        float fx = (float)(xb + dx) * (127.0f / 1023.0f);
        int x0 = min((int)fx, 127);
        int x1 = min(x0 + 1, 127);
        float wx = fx - (float)x0;
        float a0 = (x0 == X)     ? c0 : c1;
        float a1 = (x1 == X + 1) ? c1 : c2;
        float b0 = (x0 == X)     ? d0 : d1;
        float b1 = (x1 == X + 1) ? d1 : d2;
        float top = fmaf(wx, a1 - a0, a0);
        float bot = fmaf(wx, b1 - b0, b0);
        float p   = fmaf(wy, bot - top, top);
        if (tv[dx] == 1.0f)      { pc++; psum -= fmaxf(__logf(p), -100.0f); }
        else if (tv[dx] == 0.0f) { nc++; nsum -= fmaxf(__logf(1.0f - p), -100.0f); }
    }
    for (int o = 32; o; o >>= 1) {
        psum += __shfl_down(psum, o, 64);
        nsum += __shfl_down(nsum, o, 64);
        pc   += (unsigned)__shfl_down((int)pc, o, 64);
        nc   += (unsigned)__shfl_down((int)nc, o, 64);
    }
    __shared__ float lp[4], ln[4]; __shared__ unsigned lpc[4], lnc[4];
    int wave = threadIdx.x >> 6, lane = threadIdx.x & 63;
    if (lane == 0) { lp[wave] = psum; ln[wave] = nsum; lpc[wave] = pc; lnc[wave] = nc; }
    __syncthreads();
    if (threadIdx.x == 0) {
        atomicAdd(&bsums[b * 2],     lp[0] + lp[1] + lp[2] + lp[3]);
        atomicAdd(&bsums[b * 2 + 1], ln[0] + ln[1] + ln[2] + ln[3]);
        atomicAdd(&bcnts[b * 2],     lpc[0] + lpc[1] + lpc[2] + lpc[3]);
        atomicAdd(&bcnts[b * 2 + 1], lnc[0] + lnc[1] + lnc[2] + lnc[3]);
    }
}

__global__ void finalize_kernel(const float* __restrict__ sums, const unsigned* __restrict__ cnts,
                                const float* __restrict__ bsums, const unsigned* __restrict__ bcnts,
                                float* __restrict__ out)
{
    if (threadIdx.x == 0 && blockIdx.x == 0) {
        float loss = sums[0] / fmaxf((float)cnts[0], 1.f)
                   + sums[1] / fmaxf((float)cnts[1], 1.f);
        float bt = 0.f;
        for (int b = 0; b < 4; ++b) {
            float pos = (float)bcnts[b * 2], neg = (float)bcnts[b * 2 + 1];
            float val = fmaxf(pos + neg, 1.f);
            bt += (neg / val) * bsums[b * 2] + (pos / val) * bsums[b * 2 + 1];
        }
        out[0] = loss + bt / 2097152.0f;
    }
}

extern "C" void kernel_launch(void* const* d_in, const int* in_sizes, int n_in,
                              void* d_out, int out_size, void* d_ws, size_t ws_size,
                              hipStream_t stream)
{
    const float* mp  = (const float*)d_in[0];
    const float* cp  = (const float*)d_in[1];
    const float* bp  = (const float*)d_in[2];
    const int*   seg = (const int*)d_in[3];
    const float* bg  = (const float*)d_in[4];
    float* out = (float*)d_out;

    char* ws = (char*)d_ws;
    float* probA = (float*)(ws + OFF_PROB);
    float* nllA  = (float*)(ws + OFF_NLL);
    unsigned* ctl    = (unsigned*)(ws + OFF_CTL);
    unsigned* hist   = ctl + CTL_HIST;
    unsigned* prefix = ctl + CTL_PREFIX;
    unsigned* krem   = ctl + CTL_KREM;
    float*    thr    = (float*)(ctl + CTL_THR);
    float*    sums   = (float*)(ctl + CTL_SUM);
    unsigned* cnts   = ctl + CTL_CNT;
    float*    bsums  = (float*)(ctl + CTL_BSUM);
    unsigned* bcnts  = ctl + CTL_BCNT;

    hipMemsetAsync(ctl, 0, CTL_U32S * 4, stream);

    fused_pass1<<<dim3(2048, 2), 256, 0, stream>>>(mp, cp, seg, probA, nllA);
    boundary_kernel<<<dim3(512, 4), 256, 0, stream>>>(bp, bg, bsums, bcnts);
    for (int lvl = 0; lvl < 3; ++lvl) {
        unsigned* hl = hist + lvl * 2 * 4096;
        hist_level<<<dim3(256, 2), 256, 0, stream>>>(probA, prefix, hl, lvl);
        select_level<<<2, 256, 0, stream>>>(hl, prefix, krem, thr, lvl, lvl == 2 ? 64 : 4096);
    }
    reduce_ohem<<<dim3(256, 2), 256, 0, stream>>>(probA, nllA, thr, sums, cnts);
    finalize_kernel<<<1, 64, 0, stream>>>(sums, cnts, bsums, bcnts, out);
}

// Round 2
// 143.721 us; speedup vs baseline: 1.6680x; 1.6680x over previous
//
#include <hip/hip_runtime.h>

// Problem constants
#define NPX    2097152                // 4*512*1024 pixels per head
#define NPX4   (NPX/4)
#define CH_STR 8192                   // 64*128
#define IMG_STR 155648                // 19*8192

// Workspace layout (bytes)
#define OFF_PROB  0ull                          // 2 heads * NPX floats = 16 MB
#define OFF_NLL   (2ull*NPX*4)                  // 16 MB
#define OFF_CTL   (4ull*NPX*4)                  // control region (u32 indexed)
// ctl layout in u32 units
#define CTL_HIST    0                   // [3 levels][2 heads][4096] = 24576
#define CTL_PREFIX  24576               // u[2]
#define CTL_KREM    24578               // u[2]
#define CTL_THR     24580               // f[2]
#define CTL_DONE    24582               // u[2]   1 = thr==0.7 fast path valid
#define CTL_SUM     24584               // f[2]   (decide-kernel result)
#define CTL_CNT     24586               // u[2]
#define CTL_PPSUM   24588               // f[2*2048] pass1 per-block partial sums
#define CTL_PPCNT   28684               // u[2*2048]
#define CTL_OPSUM   32780               // f[2*256]  reduce_ohem partials (radix path)
#define CTL_OPCNT   33292               // u[2*256]
#define CTL_BPS     33804               // f[4*128*2] boundary (psum,nsum) per block
#define CTL_BPC     34828               // u[4*128*2] boundary (pc,nc) per block
#define CTL_U32S    35852

// ---------------------------------------------------------------------------
// Pass 1: upsample logits (align_corners) + log-softmax at target + store
// prob / nll arrays. Also accumulates per-block OHEM partials for the
// thr==0.7 fast path (sum/count of nll where valid && prob <= 0.7).
// No atomics anywhere: partials go to private slots.
// ---------------------------------------------------------------------------
__global__ __launch_bounds__(256) void fused_pass1(
    const float* __restrict__ mp, const float* __restrict__ cp,
    const int* __restrict__ seg, float* __restrict__ probA, float* __restrict__ nllA,
    float* __restrict__ ppsum, unsigned* __restrict__ ppcnt)
{
    const float* pred = blockIdx.y ? cp : mp;
    float* prob = probA + (size_t)blockIdx.y * NPX;
    float* nll  = nllA  + (size_t)blockIdx.y * NPX;

    int g  = blockIdx.x * 256 + threadIdx.x;
    int P  = g << 2;
    int b  = P >> 19;
    int rem = P & 0x7FFFF;
    int y  = rem >> 10;
    int xb = rem & 1023;

    float fy = (float)y * (63.0f / 511.0f);
    int y0 = min((int)fy, 63);
    int y1 = min(y0 + 1, 63);
    float wy = fy - (float)y0;

    float wx[4]; bool s0m[4], s1m[4];
    float fx0 = (float)xb * (127.0f / 1023.0f);
    int X  = min((int)fx0, 126);          // x0 of first px; X+1 <= 127 always
    int X2 = min(X + 2, 127);
#pragma unroll
    for (int dx = 0; dx < 4; ++dx) {
        float fx = (float)(xb + dx) * (127.0f / 1023.0f);
        int x0 = min((int)fx, 127);
        int x1 = min(x0 + 1, 127);
        wx[dx]  = fx - (float)x0;
        s0m[dx] = (x0 == X);
        s1m[dx] = (x1 == X + 1);
    }

    int4 t4 = *(const int4*)(seg + P);
    int t[4] = {t4.x, t4.y, t4.z, t4.w};

    float s[4]  = {0.f, 0.f, 0.f, 0.f};
    float lt[4] = {0.f, 0.f, 0.f, 0.f};

    const float* r0 = pred + (size_t)b * IMG_STR + y0 * 128;
    const float* r1 = pred + (size_t)b * IMG_STR + y1 * 128;

    for (int c = 0; c < 19; ++c) {
        float c0 = r0[X], c1 = r0[X + 1], c2 = r0[X2];
        float d0 = r1[X], d1 = r1[X + 1], d2 = r1[X2];
#pragma unroll
        for (int dx = 0; dx < 4; ++dx) {
            float a0 = s0m[dx] ? c0 : c1;
            float a1 = s1m[dx] ? c1 : c2;
            float b0 = s0m[dx] ? d0 : d1;
            float b1 = s1m[dx] ? d1 : d2;
            float top = fmaf(wx[dx], a1 - a0, a0);
            float bot = fmaf(wx[dx], b1 - b0, b0);
            float l   = fmaf(wy, bot - top, top);
            s[dx] += __expf(l);
            lt[dx] = (c == t[dx]) ? l : lt[dx];
        }
        r0 += CH_STR; r1 += CH_STR;
    }

    float pr[4], nl[4];
    float fs = 0.f; unsigned ic = 0;
#pragma unroll
    for (int dx = 0; dx < 4; ++dx) {
        float ls = __logf(s[dx]);
        float n  = ls - lt[dx];                 // -log softmax at target
        float p  = fminf(__expf(-n), 1.0f);     // prob at target, <= 1.0
        if (t[dx] == 255) { p = 1.0f; n = -1.0f; }   // invalid sentinel
        pr[dx] = p; nl[dx] = n;
        if (p <= 0.7f && n >= 0.f) { fs += n; ic++; }   // thr==0.7 fast path
    }
    *(float4*)(prob + P) = make_float4(pr[0], pr[1], pr[2], pr[3]);
    *(float4*)(nll  + P) = make_float4(nl[0], nl[1], nl[2], nl[3]);

    // block reduction of (fs, ic) -> private partial slot, no atomics
    for (int o = 32; o; o >>= 1) {
        fs += __shfl_down(fs, o, 64);
        ic += (unsigned)__shfl_down((int)ic, o, 64);
    }
    __shared__ float lf[4]; __shared__ unsigned li[4];
    int wave = threadIdx.x >> 6, lane = threadIdx.x & 63;
    if (lane == 0) { lf[wave] = fs; li[wave] = ic; }
    __syncthreads();
    if (threadIdx.x == 0) {
        ppsum[blockIdx.y * 2048 + blockIdx.x] = lf[0] + lf[1] + lf[2] + lf[3];
        ppcnt[blockIdx.y * 2048 + blockIdx.x] = li[0] + li[1] + li[2] + li[3];
    }
}

// ---------------------------------------------------------------------------
// Decide: reduce pass1 partials. If count(prob<=0.7) >= MIN_KEPT the exact
// threshold is 0.7 and sums are final (done=1, radix kernels early-return).
// Otherwise zero the radix histograms for the slow path.
// ---------------------------------------------------------------------------
__global__ __launch_bounds__(256) void decide_kernel(
    const float* __restrict__ ppsum, const unsigned* __restrict__ ppcnt,
    unsigned* __restrict__ done, float* __restrict__ thr,
    float* __restrict__ sums, unsigned* __restrict__ cnts,
    unsigned* __restrict__ hist)
{
    __shared__ float lf[256]; __shared__ unsigned lu[256];
    __shared__ unsigned needHist;
    if (threadIdx.x == 0) needHist = 0;
    for (int h = 0; h < 2; ++h) {
        float s = 0.f; unsigned c = 0;
        for (int i = threadIdx.x; i < 2048; i += 256) {
            s += ppsum[h * 2048 + i];
            c += ppcnt[h * 2048 + i];
        }
        lf[threadIdx.x] = s; lu[threadIdx.x] = c;
        __syncthreads();
        for (int o = 128; o; o >>= 1) {
            if (threadIdx.x < o) { lf[threadIdx.x] += lf[threadIdx.x + o]; lu[threadIdx.x] += lu[threadIdx.x + o]; }
            __syncthreads();
        }
        if (threadIdx.x == 0) {
            if (lu[0] >= 100000u) { done[h] = 1u; thr[h] = 0.7f; sums[h] = lf[0]; cnts[h] = lu[0]; }
            else                  { done[h] = 0u; needHist = 1u; }
        }
        __syncthreads();
    }
    if (needHist) {
        for (int i = threadIdx.x; i < 24576; i += 256) hist[i] = 0u;
    }
}

// ---------------------------------------------------------------------------
// Radix-select histograms over float bit patterns (monotone for x >= 0).
// Level 0: bits[31:18], level 1: bits[17:6], level 2: bits[5:0].
// Only runs when done[head]==0 (rare path).
// ---------------------------------------------------------------------------
__global__ __launch_bounds__(256) void hist_level(
    const float* __restrict__ probA, const unsigned* __restrict__ prefixA,
    const unsigned* __restrict__ doneA, unsigned* __restrict__ histA, int level)
{
    int head = blockIdx.y;
    if (doneA[head]) return;
    __shared__ unsigned h[4096];
    const float4* prob = (const float4*)(probA + (size_t)head * NPX);
    unsigned* gh = histA + head * 4096;
    unsigned prefix = prefixA[head];
    for (int i = threadIdx.x; i < 4096; i += 256) h[i] = 0;
    __syncthreads();
    int stride = gridDim.x * 256;
    for (int i = blockIdx.x * 256 + threadIdx.x; i < NPX4; i += stride) {
        float4 p = prob[i];
        unsigned u[4] = {__float_as_uint(p.x), __float_as_uint(p.y),
                         __float_as_uint(p.z), __float_as_uint(p.w)};
#pragma unroll
        for (int k = 0; k < 4; ++k) {
            unsigned bv = u[k];
            if (level == 0) {
                atomicAdd(&h[bv >> 18], 1u);
            } else if (level == 1) {
                if ((bv >> 18) == prefix) atomicAdd(&h[(bv >> 6) & 0xFFFu], 1u);
            } else {
                if ((bv >> 6) == prefix) atomicAdd(&h[bv & 63u], 1u);
            }
        }
    }
    __syncthreads();
    for (int i = threadIdx.x; i < 4096; i += 256) {
        unsigned v = h[i];
        if (v) atomicAdd(&gh[i], v);
    }
}

__global__ __launch_bounds__(256) void select_level(
    const unsigned* __restrict__ histA, const unsigned* __restrict__ doneA,
    unsigned* __restrict__ prefixA, unsigned* __restrict__ kremA,
    float* __restrict__ thrA, int level, int bins)
{
    int head = blockIdx.x;
    if (doneA[head]) return;
    const unsigned* h = histA + head * 4096;
    __shared__ unsigned chunk[256];
    __shared__ unsigned cpre[257];
    __shared__ float foundThr;
    if (threadIdx.x == 0) foundThr = 0.7f;

    int per  = (bins + 255) >> 8;
    int base = threadIdx.x * per;
    unsigned sum = 0;
    for (int i = 0; i < per; ++i) { int idx = base + i; if (idx < bins) sum += h[idx]; }
    chunk[threadIdx.x] = sum;
    __syncthreads();
    if (threadIdx.x == 0) {
        unsigned acc = 0;
        for (int i = 0; i < 256; ++i) { cpre[i] = acc; acc += chunk[i]; }
        cpre[256] = acc;
    }
    __syncthreads();
    unsigned K = (level == 0) ? 100000u : kremA[head];
    if (K > 0 && cpre[threadIdx.x] < K && K <= cpre[threadIdx.x + 1]) {
        unsigned acc = cpre[threadIdx.x];
        for (int i = 0; i < per; ++i) {
            int idx = base + i;
            unsigned c = (idx < bins) ? h[idx] : 0u;
            if (acc < K && K <= acc + c) {
                if (level == 0) {
                    prefixA[head] = (unsigned)idx; kremA[head] = K - acc;
                } else if (level == 1) {
                    prefixA[head] = (prefixA[head] << 12) | (unsigned)idx;
                    kremA[head] = K - acc;
                } else {
                    unsigned bitsv = (prefixA[head] << 6) | (unsigned)idx;
                    foundThr = fmaxf(0.7f, __uint_as_float(bitsv));
                }
                break;
            }
            acc += c;
        }
    }
    __syncthreads();
    if (level == 2 && threadIdx.x == 0) thrA[head] = foundThr;
}

// ---------------------------------------------------------------------------
// OHEM reduction for the radix path only (done==0). Partials, no atomics.
// ---------------------------------------------------------------------------
__global__ __launch_bounds__(256) void reduce_ohem(
    const float* __restrict__ probA, const float* __restrict__ nllA,
    const float* __restrict__ thrA, const unsigned* __restrict__ doneA,
    float* __restrict__ opsum, unsigned* __restrict__ opcnt)
{
    int head = blockIdx.y;
    if (doneA[head]) return;
    float thr = thrA[head];
    const float4* prob = (const float4*)(probA + (size_t)head * NPX);
    const float4* nl4  = (const float4*)(nllA  + (size_t)head * NPX);
    float fs = 0.f; unsigned ic = 0;
    int stride = gridDim.x * 256;
    for (int i = blockIdx.x * 256 + threadIdx.x; i < NPX4; i += stride) {
        float4 p = prob[i]; float4 n = nl4[i];
        if (p.x <= thr && n.x >= 0.f) { fs += n.x; ic++; }
        if (p.y <= thr && n.y >= 0.f) { fs += n.y; ic++; }
        if (p.z <= thr && n.z >= 0.f) { fs += n.z; ic++; }
        if (p.w <= thr && n.w >= 0.f) { fs += n.w; ic++; }
    }
    for (int o = 32; o; o >>= 1) {
        fs += __shfl_down(fs, o, 64);
        ic += (unsigned)__shfl_down((int)ic, o, 64);
    }
    __shared__ float lf[4]; __shared__ unsigned li[4];
    int wave = threadIdx.x >> 6, lane = threadIdx.x & 63;
    if (lane == 0) { lf[wave] = fs; li[wave] = ic; }
    __syncthreads();
    if (threadIdx.x == 0) {
        opsum[head * 256 + blockIdx.x] = lf[0] + lf[1] + lf[2] + lf[3];
        opcnt[head * 256 + blockIdx.x] = li[0] + li[1] + li[2] + li[3];
    }
}

// ---------------------------------------------------------------------------
// Boundary BCE: grid-stride, per-block private partials, no atomics.
// ---------------------------------------------------------------------------
__global__ __launch_bounds__(256) void boundary_kernel(
    const float* __restrict__ bp, const float* __restrict__ bg,
    float* __restrict__ bps, unsigned* __restrict__ bpc)
{
    int b = blockIdx.y;
    float psum = 0.f, nsum = 0.f; unsigned pc = 0, nc = 0;

    for (int g = blockIdx.x * 256 + threadIdx.x; g < 131072; g += 128 * 256) {
        int P = g << 2;                 // within-sample pixel index
        int y = P >> 10, xb = P & 1023;

        float fy = (float)y * (63.0f / 511.0f);
        int y0 = min((int)fy, 63);
        int y1 = min(y0 + 1, 63);
        float wy = fy - (float)y0;

        const float* r0 = bp + b * 8192 + y0 * 128;
        const float* r1 = bp + b * 8192 + y1 * 128;
        float fx0 = (float)xb * (127.0f / 1023.0f);
        int X  = min((int)fx0, 126);
        int X2 = min(X + 2, 127);
        float c0 = r0[X], c1 = r0[X + 1], c2 = r0[X2];
        float d0 = r1[X], d1 = r1[X + 1], d2 = r1[X2];

        float4 t4 = *(const float4*)(bg + (size_t)b * 524288 + P);
        float tv[4] = {t4.x, t4.y, t4.z, t4.w};

#pragma unroll
        for (int dx = 0; dx < 4; ++dx) {
            float fx = (float)(xb + dx) * (127.0f / 1023.0f);
            int x0 = min((int)fx, 127);
            int x1 = min(x0 + 1, 127);
            float wx = fx - (float)x0;
            float a0 = (x0 == X)     ? c0 : c1;
            float a1 = (x1 == X + 1) ? c1 : c2;
            float b0 = (x0 == X)     ? d0 : d1;
            float b1 = (x1 == X + 1) ? d1 : d2;
            float top = fmaf(wx, a1 - a0, a0);
            float bot = fmaf(wx, b1 - b0, b0);
            float p   = fmaf(wy, bot - top, top);
            if (tv[dx] == 1.0f)      { pc++; psum -= fmaxf(__logf(p), -100.0f); }
            else if (tv[dx] == 0.0f) { nc++; nsum -= fmaxf(__logf(1.0f - p), -100.0f); }
        }
    }
    for (int o = 32; o; o >>= 1) {
        psum += __shfl_down(psum, o, 64);
        nsum += __shfl_down(nsum, o, 64);
        pc   += (unsigned)__shfl_down((int)pc, o, 64);
        nc   += (unsigned)__shfl_down((int)nc, o, 64);
    }
    __shared__ float lp[4], ln[4]; __shared__ unsigned lpc[4], lnc[4];
    int wave = threadIdx.x >> 6, lane = threadIdx.x & 63;
    if (lane == 0) { lp[wave] = psum; ln[wave] = nsum; lpc[wave] = pc; lnc[wave] = nc; }
    __syncthreads();
    if (threadIdx.x == 0) {
        int slot = b * 128 + blockIdx.x;
        bps[2 * slot]     = lp[0] + lp[1] + lp[2] + lp[3];
        bps[2 * slot + 1] = ln[0] + ln[1] + ln[2] + ln[3];
        bpc[2 * slot]     = lpc[0] + lpc[1] + lpc[2] + lpc[3];
        bpc[2 * slot + 1] = lnc[0] + lnc[1] + lnc[2] + lnc[3];
    }
}

// ---------------------------------------------------------------------------
// Finalize: one block combines everything.
// ---------------------------------------------------------------------------
__global__ __launch_bounds__(256) void finalize_kernel(
    const unsigned* __restrict__ done, const float* __restrict__ sums,
    const unsigned* __restrict__ cnts,
    const float* __restrict__ opsum, const unsigned* __restrict__ opcnt,
    const float* __restrict__ bps, const unsigned* __restrict__ bpc,
    float* __restrict__ out)
{
    __shared__ float lf[256]; __shared__ unsigned lu[256];
    __shared__ float headLoss[2];
    __shared__ float Pb[4], Nb[4]; __shared__ unsigned PCb[4], NCb[4];

    for (int h = 0; h < 2; ++h) {
        unsigned d = done[h];
        lf[threadIdx.x] = d ? 0.f : opsum[h * 256 + threadIdx.x];
        lu[threadIdx.x] = d ? 0u  : opcnt[h * 256 + threadIdx.x];
        __syncthreads();
        for (int o = 128; o; o >>= 1) {
            if (threadIdx.x < o) { lf[threadIdx.x] += lf[threadIdx.x + o]; lu[threadIdx.x] += lu[threadIdx.x + o]; }
            __syncthreads();
        }
        if (threadIdx.x == 0) {
            float S = d ? sums[h] : lf[0];
            unsigned C = d ? cnts[h] : lu[0];
            headLoss[h] = S / fmaxf((float)C, 1.f);
        }
        __syncthreads();
    }

    for (int b = 0; b < 4; ++b) {
        float ps = 0.f, ns = 0.f; unsigned p_c = 0, n_c = 0;
        if (threadIdx.x < 128) {
            int j = b * 128 + threadIdx.x;
            ps = bps[2 * j]; ns = bps[2 * j + 1];
            p_c = bpc[2 * j]; n_c = bpc[2 * j + 1];
        }
        lf[threadIdx.x] = ps; lu[threadIdx.x] = p_c;
        __syncthreads();
        for (int o = 128; o; o >>= 1) {
            if (threadIdx.x < o) { lf[threadIdx.x] += lf[threadIdx.x + o]; lu[threadIdx.x] += lu[threadIdx.x + o]; }
            __syncthreads();
        }
        if (threadIdx.x == 0) { Pb[b] = lf[0]; PCb[b] = lu[0]; }
        __syncthreads();
        lf[threadIdx.x] = ns; lu[threadIdx.x] = n_c;
        __syncthreads();
        for (int o = 128; o; o >>= 1) {
            if (threadIdx.x < o) { lf[threadIdx.x] += lf[threadIdx.x + o]; lu[threadIdx.x] += lu[threadIdx.x + o]; }
            __syncthreads();
        }
        if (threadIdx.x == 0) { Nb[b] = lf[0]; NCb[b] = lu[0]; }
        __syncthreads();
    }

    if (threadIdx.x == 0) {
        float bt = 0.f;
        for (int b = 0; b < 4; ++b) {
            float pos = (float)PCb[b], neg = (float)NCb[b];
            float val = fmaxf(pos + neg, 1.f);
            bt += (neg / val) * Pb[b] + (pos / val) * Nb[b];
        }
        out[0] = headLoss[0] + headLoss[1] + bt / 2097152.0f;
    }
}

extern "C" void kernel_launch(void* const* d_in, const int* in_sizes, int n_in,
                              void* d_out, int out_size, void* d_ws, size_t ws_size,
                              hipStream_t stream)
{
    const float* mp  = (const float*)d_in[0];
    const float* cp  = (const float*)d_in[1];
    const float* bp  = (const float*)d_in[2];
    const int*   seg = (const int*)d_in[3];
    const float* bg  = (const float*)d_in[4];
    float* out = (float*)d_out;

    char* ws = (char*)d_ws;
    float* probA = (float*)(ws + OFF_PROB);
    float* nllA  = (float*)(ws + OFF_NLL);
    unsigned* ctl    = (unsigned*)(ws + OFF_CTL);
    unsigned* hist   = ctl + CTL_HIST;
    unsigned* prefix = ctl + CTL_PREFIX;
    unsigned* krem   = ctl + CTL_KREM;
    float*    thr    = (float*)(ctl + CTL_THR);
    unsigned* done   = ctl + CTL_DONE;
    float*    sums   = (float*)(ctl + CTL_SUM);
    unsigned* cnts   = ctl + CTL_CNT;
    float*    ppsum  = (float*)(ctl + CTL_PPSUM);
    unsigned* ppcnt  = ctl + CTL_PPCNT;
    float*    opsum  = (float*)(ctl + CTL_OPSUM);
    unsigned* opcnt  = ctl + CTL_OPCNT;
    float*    bps    = (float*)(ctl + CTL_BPS);
    unsigned* bpc    = ctl + CTL_BPC;

    fused_pass1<<<dim3(2048, 2), 256, 0, stream>>>(mp, cp, seg, probA, nllA, ppsum, ppcnt);
    decide_kernel<<<1, 256, 0, stream>>>(ppsum, ppcnt, done, thr, sums, cnts, hist);
    boundary_kernel<<<dim3(128, 4), 256, 0, stream>>>(bp, bg, bps, bpc);
    for (int lvl = 0; lvl < 3; ++lvl) {
        unsigned* hl = hist + lvl * 2 * 4096;
        hist_level<<<dim3(256, 2), 256, 0, stream>>>(probA, prefix, done, hl, lvl);
        select_level<<<2, 256, 0, stream>>>(hl, done, prefix, krem, thr, lvl, lvl == 2 ? 64 : 4096);
    }
    reduce_ohem<<<dim3(256, 2), 256, 0, stream>>>(probA, nllA, thr, done, opsum, opcnt);
    finalize_kernel<<<1, 256, 0, stream>>>(done, sums, cnts, opsum, opcnt, bps, bpc, out);
}